// Round 13
// baseline (201.853 us; speedup 1.0000x reference)
//
#include <hip/hip_runtime.h>

#define NROWS 262144
#define KK 10
#define BB 3.0f
#define SROW 260                   // f16 units per row region (8 slots of 32 + 4 pad)
#define SEGF16 (16 * SROW)         // 4160 f16 = 8320 B per tile segment
#define NBLOCKS (NROWS / 32)       // 8192
#define SENT 0.54132485f           // ln(e-1): softplus(SENT) == 1.0 (boundary derivative)

typedef _Float16 v8h __attribute__((ext_vector_type(8)));
typedef _Float16 v4h __attribute__((ext_vector_type(4)));
typedef float v4f __attribute__((ext_vector_type(4)));

// d_ws layout: v8h frags: W0[4*64] | W1[2*4*64] | WC[2*16*64] ; then f32 slots[64] | ticket
#define W0_OFF 0
#define W1_OFF 256
#define WC_OFF 768
#define FRAG_TOTAL 2816
#define SLOTS_OFF (FRAG_TOTAL * 4)   // f32 units from ws base (FRAG_TOTAL*16 bytes)

__device__ __forceinline__ float fast_tanh(float a) {
    float e = __expf(2.0f * a);
    return 1.0f - __fdividef(2.0f, e + 1.0f);
}

__device__ __forceinline__ float softplus1(float v) {
    return fmaxf(v, 0.0f) + __logf(1.0f + __expf(-fabsf(v)));
}

// ---- prep: pack B-fragments with bias folded into k=8/k=50 row; zero slots + ticket ----
__global__ __launch_bounds__(256) void nsf_prep(
    const float* __restrict__ w0, const float* __restrict__ b0,
    const float* __restrict__ w1, const float* __restrict__ b1,
    const float* __restrict__ ww, const float* __restrict__ bw,
    const float* __restrict__ wh, const float* __restrict__ bh,
    const float* __restrict__ wd, const float* __restrict__ bd,
    v8h* __restrict__ wsv, float* __restrict__ wsf)
{
    const int t = blockIdx.x * 256 + threadIdx.x;
    if (t < 65) wsf[SLOTS_OFF + t] = 0.0f;   // 64 slots + ticket (float 0.0 == uint 0)
    if (t >= FRAG_TOTAL) return;

    v8h v;
    #pragma unroll
    for (int j = 0; j < 8; ++j) v[j] = (_Float16)0.0f;

    if (t < W1_OFF) {                       // W0: 9x50 (row 8 = b0) padded to K=32, 4 col tiles
        const int tile = t >> 6, lane = t & 63, q = lane >> 4, n = tile * 16 + (lane & 15);
        if (n < 50) {
            #pragma unroll
            for (int j = 0; j < 8; ++j) {
                const int k = q * 8 + j;
                if (k < 8)       v[j] = (_Float16)w0[k * 50 + n];
                else if (k == 8) v[j] = (_Float16)b0[n];
            }
        }
    } else if (t < WC_OFF) {                // W1: 51x50 (row 50 = b1), 2 k-steps, 4 col tiles
        int p = t - W1_OFF;
        const int step = p >> 8; p &= 255;
        const int tile = p >> 6, lane = p & 63, q = lane >> 4, n = tile * 16 + (lane & 15);
        if (n < 50) {
            #pragma unroll
            for (int j = 0; j < 8; ++j) {
                const int k = step * 32 + q * 8 + j;
                if (k < 50)       v[j] = (_Float16)w1[k * 50 + n];
                else if (k == 50) v[j] = (_Float16)b1[n];
            }
        }
    } else {                                // WC: 51x256 (row 50 = bias), cols c' = d*32 + jj
        int p = t - WC_OFF;
        const int step = p >> 10; p &= 1023;
        const int tile = p >> 6, lane = p & 63, q = lane >> 4;
        const int cp = tile * 16 + (lane & 15);
        const int d = cp >> 5, jj = cp & 31;
        #pragma unroll
        for (int j = 0; j < 8; ++j) {
            const int k = step * 32 + q * 8 + j;
            float val = 0.0f;
            if (k < 50) {
                if (jj < 10)      val = ww[k * 80 + d * 10 + jj];
                else if (jj < 20) val = wh[k * 80 + d * 10 + (jj - 10)];
                else if (jj < 29) val = wd[k * 72 + d * 9 + (jj - 20)];
            } else if (k == 50) {
                if (jj < 10)      val = bw[d * 10 + jj];
                else if (jj < 20) val = bh[d * 10 + (jj - 10)];
                else if (jj < 29) val = bd[d * 9 + (jj - 20)];
            }
            v[j] = (_Float16)val;
        }
    }
    wsv[t] = v;
}

// ---- main: 1 wave/block, 2 independent 16-row tiles; fence-free last-block reduction ----
__global__ __launch_bounds__(64, 2) void nsf_main(
    const float* __restrict__ x,
    const v8h* __restrict__ wsv,
    float* __restrict__ out, float* __restrict__ slots, float* __restrict__ ldp)
{
    __shared__ __align__(16) _Float16 smem[2 * SEGF16];   // 16640 B -> 9 blocks/CU
    const int lane = threadIdx.x & 63;
    const int q = lane >> 4, l15 = lane & 15;
    _Float16* segA = &smem[0];
    _Float16* segB = &smem[SEGF16];
    const int R0 = blockIdx.x * 32;                       // tile A: R0.., tile B: R0+16..

    const float4* xv = (const float4*)x;
    float4* ov = (float4*)out;

    // prefetch epilogue u values (4 tasks) early
    const float uA0 = x[(R0 + l15) * 16 + 8 + q];
    const float uA1 = x[(R0 + l15) * 16 + 12 + q];
    const float uB0 = x[(R0 + 16 + l15) * 16 + 8 + q];
    const float uB1 = x[(R0 + 16 + l15) * 16 + 12 + q];

    // passthrough of the 8 scale dims: all 64 lanes cover 32 rows x 2 float4
    {
        const int gg = R0 + (lane >> 1);
        const int part = lane & 1;
        ov[gg * 4 + part] = xv[gg * 4 + part];
    }

    // ---- phase 0: zd A-fragments for both tiles (k<8 real, k=8 -> 1.0 bias row) ----
    v8h aA, aB;
    #pragma unroll
    for (int j = 0; j < 8; ++j) { aA[j] = (_Float16)0.0f; aB[j] = (_Float16)0.0f; }
    if (lane < 16) {
        const float4 f0 = xv[(R0 + lane) * 4 + 0];
        const float4 f1 = xv[(R0 + lane) * 4 + 1];
        aA[0] = (_Float16)f0.x; aA[1] = (_Float16)f0.y; aA[2] = (_Float16)f0.z; aA[3] = (_Float16)f0.w;
        aA[4] = (_Float16)f1.x; aA[5] = (_Float16)f1.y; aA[6] = (_Float16)f1.z; aA[7] = (_Float16)f1.w;
        const float4 g0 = xv[(R0 + 16 + lane) * 4 + 0];
        const float4 g1 = xv[(R0 + 16 + lane) * 4 + 1];
        aB[0] = (_Float16)g0.x; aB[1] = (_Float16)g0.y; aB[2] = (_Float16)g0.z; aB[3] = (_Float16)g0.w;
        aB[4] = (_Float16)g1.x; aB[5] = (_Float16)g1.y; aB[6] = (_Float16)g1.z; aB[7] = (_Float16)g1.w;
    }
    if (q == 1) { aA[0] = (_Float16)1.0f; aB[0] = (_Float16)1.0f; }   // k=8: bias row

    // ---- phase 1: h1 = tanh(zd @ [w0;b0]) -> seg row-major [m][k], stride 72 ----
    #pragma unroll
    for (int t = 0; t < 4; ++t) {
        const v8h b = wsv[W0_OFF + t * 64 + lane];
        v4f cA = __builtin_amdgcn_mfma_f32_16x16x32_f16(aA, b, (v4f)(0.0f), 0, 0, 0);
        v4f cB = __builtin_amdgcn_mfma_f32_16x16x32_f16(aB, b, (v4f)(0.0f), 0, 0, 0);
        const int n = t * 16 + l15;
        #pragma unroll
        for (int rg = 0; rg < 4; ++rg) {
            segA[(q * 4 + rg) * 72 + n] = (_Float16)fast_tanh(cA[rg]);
            segB[(q * 4 + rg) * 72 + n] = (_Float16)fast_tanh(cB[rg]);
        }
    }

    // ---- phase 2: h2 = tanh(h1 @ [w1;b1]) ----
    v8h A0A, A1A, A0B, A1B;
    {
        A0A = *(const v8h*)&segA[l15 * 72 + q * 8];
        A1A = *(const v8h*)&segA[l15 * 72 + 32 + q * 8];
        A0B = *(const v8h*)&segB[l15 * 72 + q * 8];
        A1B = *(const v8h*)&segB[l15 * 72 + 32 + q * 8];
        if (q == 2) { A1A[2] = (_Float16)1.0f; A1B[2] = (_Float16)1.0f; }   // k=50: bias row
        #pragma unroll
        for (int t = 0; t < 4; ++t) {
            const v8h bf0 = wsv[W1_OFF + t * 64 + lane];
            const v8h bf1 = wsv[W1_OFF + 256 + t * 64 + lane];
            v4f cA = __builtin_amdgcn_mfma_f32_16x16x32_f16(A0A, bf0, (v4f)(0.0f), 0, 0, 0);
            cA = __builtin_amdgcn_mfma_f32_16x16x32_f16(A1A, bf1, cA, 0, 0, 0);
            v4f cB = __builtin_amdgcn_mfma_f32_16x16x32_f16(A0B, bf0, (v4f)(0.0f), 0, 0, 0);
            cB = __builtin_amdgcn_mfma_f32_16x16x32_f16(A1B, bf1, cB, 0, 0, 0);
            const int n = t * 16 + l15;
            #pragma unroll
            for (int rg = 0; rg < 4; ++rg) {
                segA[(q * 4 + rg) * 72 + n] = (_Float16)fast_tanh(cA[rg]);
                segB[(q * 4 + rg) * 72 + n] = (_Float16)fast_tanh(cB[rg]);
            }
        }
    }

    // ---- phase 3: proj -> seg slots [row*260 + d*32 + j] ----
    {
        A0A = *(const v8h*)&segA[l15 * 72 + q * 8];
        A1A = *(const v8h*)&segA[l15 * 72 + 32 + q * 8];
        A0B = *(const v8h*)&segB[l15 * 72 + q * 8];
        A1B = *(const v8h*)&segB[l15 * 72 + 32 + q * 8];
        if (q == 2) { A1A[2] = (_Float16)1.0f; A1B[2] = (_Float16)1.0f; }   // k=50: bias row
        #pragma unroll 2
        for (int t = 0; t < 16; ++t) {
            const v8h bf0 = wsv[WC_OFF + t * 64 + lane];
            const v8h bf1 = wsv[WC_OFF + 1024 + t * 64 + lane];
            v4f cA = __builtin_amdgcn_mfma_f32_16x16x32_f16(A0A, bf0, (v4f)(0.0f), 0, 0, 0);
            cA = __builtin_amdgcn_mfma_f32_16x16x32_f16(A1A, bf1, cA, 0, 0, 0);
            v4f cB = __builtin_amdgcn_mfma_f32_16x16x32_f16(A0B, bf0, (v4f)(0.0f), 0, 0, 0);
            cB = __builtin_amdgcn_mfma_f32_16x16x32_f16(A1B, bf1, cB, 0, 0, 0);
            const int cp = t * 16 + l15;
            #pragma unroll
            for (int rg = 0; rg < 4; ++rg) {
                segA[(q * 4 + rg) * SROW + cp] = (_Float16)cA[rg];
                segB[(q * 4 + rg) * SROW + cp] = (_Float16)cB[rg];
            }
        }
    }

    // ---- epilogue: 4 (tile, row, dim) tasks per lane; unroll 2 -> two independent chains ----
    float ldacc = 0.0f;
    #pragma unroll 2
    for (int task = 0; task < 4; ++task) {
        const int tile = task >> 1, tt = task & 1;
        const int d = q + tt * 4;             // 0..7
        const int g = R0 + tile * 16 + l15;
        const float ud = (tile == 0) ? (tt == 0 ? uA0 : uA1) : (tt == 0 ? uB0 : uB1);
        const _Float16* sg = (tile == 0) ? segA : segB;
        const int base = l15 * SROW + d * 32;

        float vals[32];
        #pragma unroll
        for (int blk = 0; blk < 8; ++blk) {
            const v4h p = *(const v4h*)&sg[base + blk * 4];
            vals[4 * blk + 0] = (float)p[0];
            vals[4 * blk + 1] = (float)p[1];
            vals[4 * blk + 2] = (float)p[2];
            vals[4 * blk + 3] = (float)p[3];
        }
        // vals[0..9]=aw logits, [10..19]=ah logits, [20..28]=ad raw

        float mw = vals[0];
        #pragma unroll
        for (int i = 1; i < KK; ++i) mw = fmaxf(mw, vals[i]);
        float sw = 0.0f;
        #pragma unroll
        for (int i = 0; i < KK; ++i) { vals[i] = __expf(6.0f * (vals[i] - mw)); sw += vals[i]; }
        const float invw = __fdividef(1.0f, sw);

        float mh = vals[10];
        #pragma unroll
        for (int i = 1; i < KK; ++i) mh = fmaxf(mh, vals[10 + i]);
        float sh = 0.0f;
        #pragma unroll
        for (int i = 0; i < KK; ++i) { vals[10 + i] = __expf(6.0f * (vals[10 + i] - mh)); sh += vals[10 + i]; }
        const float invh = __fdividef(1.0f, sh);

        const float uc = fminf(fmaxf(ud, -BB), BB);
        const bool inside = (ud > -BB) && (ud < BB);

        // streaming bin search over RAW derivative values (sentinel: softplus(SENT)==1)
        float cw = 0.0f, ch = 0.0f;
        float xprev = -BB, yprev = -BB, rprev = SENT;
        float xk = -BB, yk = -BB, wk = 1.0f, hk2 = 1.0f, rdk = SENT, rdk1 = SENT;
        #pragma unroll
        for (int i = 0; i < KK; ++i) {
            cw += vals[i] * invw;
            ch += vals[10 + i] * invh;
            const float xnext = fmaf(6.0f, cw, -BB);
            const float ynext = fmaf(6.0f, ch, -BB);
            const float rnext = (i == KK - 1) ? SENT : vals[20 + i];
            const bool c = (i == 0) || (uc >= xprev);
            if (c) { xk = xprev; yk = yprev; wk = xnext - xprev; hk2 = ynext - yprev; rdk = rprev; rdk1 = rnext; }
            xprev = xnext; yprev = ynext; rprev = rnext;
        }
        const float dk = softplus1(rdk);
        const float dk1 = softplus1(rdk1);

        const float rwk = __fdividef(1.0f, wk);
        const float sk = hk2 * rwk;
        const float xi = (uc - xk) * rwk;
        const float om = 1.0f - xi;
        const float denom = sk + (dk1 + dk - 2.0f * sk) * xi * om;
        const float rden = __fdividef(1.0f, denom);
        const float ynum = sk * xi * xi + dk * xi * om;
        const float yv = yk + hk2 * ynum * rden;
        const float larg = dk1 * xi * xi + 2.0f * sk * xi * om + dk * om * om;
        const float ldet = __logf(sk * sk * larg * rden * rden);

        out[g * 16 + 8 + d] = inside ? yv : ud;
        ldacc += inside ? ldet : 0.0f;
    }

    // ---- logdet: wave reduce -> slot atomic -> waitcnt-ordered ticket; last block sums ----
    #pragma unroll
    for (int off = 32; off > 0; off >>= 1) ldacc += __shfl_down(ldacc, off);
    int lastflag = 0;
    if (lane == 0) {
        atomicAdd(&slots[blockIdx.x & 63], ldacc);
        __builtin_amdgcn_s_waitcnt(0);   // drain own atomic to coherence point (no cache writeback)
        const unsigned int old = atomicAdd((unsigned int*)(slots + 64), 1u);
        lastflag = (old == NBLOCKS - 1) ? 1 : 0;
    }
    lastflag = __shfl(lastflag, 0);
    if (lastflag) {
        float v = atomicAdd(&slots[lane], 0.0f);   // atomic read: coherent at L2, no fence needed
        #pragma unroll
        for (int off = 32; off > 0; off >>= 1) v += __shfl_down(v, off);
        if (lane == 0) *ldp = v;
    }
}

extern "C" void kernel_launch(void* const* d_in, const int* in_sizes, int n_in,
                              void* d_out, int out_size, void* d_ws, size_t ws_size,
                              hipStream_t stream) {
    const float* x  = (const float*)d_in[0];
    const float* w0 = (const float*)d_in[1];
    const float* b0 = (const float*)d_in[2];
    const float* w1 = (const float*)d_in[3];
    const float* b1 = (const float*)d_in[4];
    const float* ww = (const float*)d_in[5];
    const float* bw = (const float*)d_in[6];
    const float* wh = (const float*)d_in[7];
    const float* bh = (const float*)d_in[8];
    const float* wd = (const float*)d_in[9];
    const float* bd = (const float*)d_in[10];

    float* out = (float*)d_out;
    float* ldp = out + (size_t)NROWS * 16;   // scalar logdet sum slot
    v8h* wsv = (v8h*)d_ws;                   // 45 KB packed B-fragments (bias folded)
    float* wsf = (float*)d_ws;               // f32 view: slots[64] + ticket
    float* slots = wsf + SLOTS_OFF;

    hipLaunchKernelGGL(nsf_prep, dim3((FRAG_TOTAL + 255) / 256), dim3(256), 0, stream,
                       w0, b0, w1, b1, ww, bw, wh, bh, wd, bd, wsv, wsf);
    hipLaunchKernelGGL(nsf_main, dim3(NBLOCKS), dim3(64), 0, stream,
                       x, wsv, out, slots, ldp);
}

// Round 14
// 160.126 us; speedup vs baseline: 1.2606x; 1.2606x over previous
//
#include <hip/hip_runtime.h>

#define NROWS 262144
#define KK 10
#define BB 3.0f
#define SROW 260                   // f16 units per row region (8 slots of 32 + 4 pad)
#define SEGF16 (16 * SROW)         // 4160 f16 = 8320 B per tile segment
#define SENT 0.54132485f           // ln(e-1): softplus(SENT) == 1.0 (boundary derivative)

typedef _Float16 v8h __attribute__((ext_vector_type(8)));
typedef _Float16 v4h __attribute__((ext_vector_type(4)));
typedef float v4f __attribute__((ext_vector_type(4)));

// d_ws layout: v8h frags: W0[4*64] | W1[2*4*64] | WC[2*16*64] ; then f32 slots[64]
#define W0_OFF 0
#define W1_OFF 256
#define WC_OFF 768
#define FRAG_TOTAL 2816
#define SLOTS_OFF (FRAG_TOTAL * 4)   // f32 units from ws base (FRAG_TOTAL*16 bytes)

__device__ __forceinline__ float fast_tanh(float a) {
    float e = __expf(2.0f * a);
    return 1.0f - __fdividef(2.0f, e + 1.0f);
}

__device__ __forceinline__ float softplus1(float v) {
    return fmaxf(v, 0.0f) + __logf(1.0f + __expf(-fabsf(v)));
}

// one (row, dim) rational-quadratic spline task; reads 32 f16 from LDS slot, writes z, adds logdet
__device__ __forceinline__ void spline_task(
    const _Float16* __restrict__ sg, int base, float ud, int g, int d,
    float* __restrict__ out, float& ldacc)
{
    float vals[32];
    #pragma unroll
    for (int blk = 0; blk < 8; ++blk) {
        const v4h p = *(const v4h*)&sg[base + blk * 4];
        vals[4 * blk + 0] = (float)p[0];
        vals[4 * blk + 1] = (float)p[1];
        vals[4 * blk + 2] = (float)p[2];
        vals[4 * blk + 3] = (float)p[3];
    }
    // vals[0..9]=aw logits, [10..19]=ah logits, [20..28]=ad raw

    float mw = vals[0];
    #pragma unroll
    for (int i = 1; i < KK; ++i) mw = fmaxf(mw, vals[i]);
    float sw = 0.0f;
    #pragma unroll
    for (int i = 0; i < KK; ++i) { vals[i] = __expf(6.0f * (vals[i] - mw)); sw += vals[i]; }
    const float invw = __fdividef(1.0f, sw);

    float mh = vals[10];
    #pragma unroll
    for (int i = 1; i < KK; ++i) mh = fmaxf(mh, vals[10 + i]);
    float sh = 0.0f;
    #pragma unroll
    for (int i = 0; i < KK; ++i) { vals[10 + i] = __expf(6.0f * (vals[10 + i] - mh)); sh += vals[10 + i]; }
    const float invh = __fdividef(1.0f, sh);

    const float uc = fminf(fmaxf(ud, -BB), BB);
    const bool inside = (ud > -BB) && (ud < BB);

    // streaming bin search over RAW derivative values (sentinel: softplus(SENT)==1)
    float cw = 0.0f, ch = 0.0f;
    float xprev = -BB, yprev = -BB, rprev = SENT;
    float xk = -BB, yk = -BB, wk = 1.0f, hk2 = 1.0f, rdk = SENT, rdk1 = SENT;
    #pragma unroll
    for (int i = 0; i < KK; ++i) {
        cw += vals[i] * invw;
        ch += vals[10 + i] * invh;
        const float xnext = fmaf(6.0f, cw, -BB);
        const float ynext = fmaf(6.0f, ch, -BB);
        const float rnext = (i == KK - 1) ? SENT : vals[20 + i];
        const bool c = (i == 0) || (uc >= xprev);
        if (c) { xk = xprev; yk = yprev; wk = xnext - xprev; hk2 = ynext - yprev; rdk = rprev; rdk1 = rnext; }
        xprev = xnext; yprev = ynext; rprev = rnext;
    }
    const float dk = softplus1(rdk);
    const float dk1 = softplus1(rdk1);

    const float rwk = __fdividef(1.0f, wk);
    const float sk = hk2 * rwk;
    const float xi = (uc - xk) * rwk;
    const float om = 1.0f - xi;
    const float denom = sk + (dk1 + dk - 2.0f * sk) * xi * om;
    const float rden = __fdividef(1.0f, denom);
    const float ynum = sk * xi * xi + dk * xi * om;
    const float yv = yk + hk2 * ynum * rden;
    const float larg = dk1 * xi * xi + 2.0f * sk * xi * om + dk * om * om;
    const float ldet = __logf(sk * sk * larg * rden * rden);

    out[g * 16 + 8 + d] = inside ? yv : ud;
    ldacc += inside ? ldet : 0.0f;
}

// ---- prep: pack B-fragments with bias folded into k=8/k=50 row; zero logdet slots ----
__global__ __launch_bounds__(256) void nsf_prep(
    const float* __restrict__ w0, const float* __restrict__ b0,
    const float* __restrict__ w1, const float* __restrict__ b1,
    const float* __restrict__ ww, const float* __restrict__ bw,
    const float* __restrict__ wh, const float* __restrict__ bh,
    const float* __restrict__ wd, const float* __restrict__ bd,
    v8h* __restrict__ wsv, float* __restrict__ wsf)
{
    const int t = blockIdx.x * 256 + threadIdx.x;
    if (t < 64) wsf[SLOTS_OFF + t] = 0.0f;
    if (t >= FRAG_TOTAL) return;

    v8h v;
    #pragma unroll
    for (int j = 0; j < 8; ++j) v[j] = (_Float16)0.0f;

    if (t < W1_OFF) {                       // W0: 9x50 (row 8 = b0) padded to K=32, 4 col tiles
        const int tile = t >> 6, lane = t & 63, q = lane >> 4, n = tile * 16 + (lane & 15);
        if (n < 50) {
            #pragma unroll
            for (int j = 0; j < 8; ++j) {
                const int k = q * 8 + j;
                if (k < 8)       v[j] = (_Float16)w0[k * 50 + n];
                else if (k == 8) v[j] = (_Float16)b0[n];
            }
        }
    } else if (t < WC_OFF) {                // W1: 51x50 (row 50 = b1), 2 k-steps, 4 col tiles
        int p = t - W1_OFF;
        const int step = p >> 8; p &= 255;
        const int tile = p >> 6, lane = p & 63, q = lane >> 4, n = tile * 16 + (lane & 15);
        if (n < 50) {
            #pragma unroll
            for (int j = 0; j < 8; ++j) {
                const int k = step * 32 + q * 8 + j;
                if (k < 50)       v[j] = (_Float16)w1[k * 50 + n];
                else if (k == 50) v[j] = (_Float16)b1[n];
            }
        }
    } else {                                // WC: 51x256 (row 50 = bias), cols c' = d*32 + jj
        int p = t - WC_OFF;
        const int step = p >> 10; p &= 1023;
        const int tile = p >> 6, lane = p & 63, q = lane >> 4;
        const int cp = tile * 16 + (lane & 15);
        const int d = cp >> 5, jj = cp & 31;
        #pragma unroll
        for (int j = 0; j < 8; ++j) {
            const int k = step * 32 + q * 8 + j;
            float val = 0.0f;
            if (k < 50) {
                if (jj < 10)      val = ww[k * 80 + d * 10 + jj];
                else if (jj < 20) val = wh[k * 80 + d * 10 + (jj - 10)];
                else if (jj < 29) val = wd[k * 72 + d * 9 + (jj - 20)];
            } else if (k == 50) {
                if (jj < 10)      val = bw[d * 10 + jj];
                else if (jj < 20) val = bh[d * 10 + (jj - 10)];
                else if (jj < 29) val = bd[d * 9 + (jj - 20)];
            }
            v[j] = (_Float16)val;
        }
    }
    wsv[t] = v;
}

// ---- main: 1 wave/block, 2 tiles; phase-3 halves interleaved with epilogue tasks ----
__global__ __launch_bounds__(64, 2) void nsf_main(
    const float* __restrict__ x,
    const v8h* __restrict__ wsv,
    float* __restrict__ out, float* __restrict__ slots)
{
    __shared__ __align__(16) _Float16 smem[2 * SEGF16];   // 16640 B -> 9 blocks/CU
    const int lane = threadIdx.x & 63;
    const int q = lane >> 4, l15 = lane & 15;
    _Float16* segA = &smem[0];
    _Float16* segB = &smem[SEGF16];
    const int R0 = blockIdx.x * 32;                       // tile A: R0.., tile B: R0+16..

    const float4* xv = (const float4*)x;
    float4* ov = (float4*)out;

    // prefetch epilogue u values (4 tasks) early
    const float uA0 = x[(R0 + l15) * 16 + 8 + q];
    const float uA1 = x[(R0 + l15) * 16 + 12 + q];
    const float uB0 = x[(R0 + 16 + l15) * 16 + 8 + q];
    const float uB1 = x[(R0 + 16 + l15) * 16 + 12 + q];

    // passthrough of the 8 scale dims: all 64 lanes cover 32 rows x 2 float4
    {
        const int gg = R0 + (lane >> 1);
        const int part = lane & 1;
        ov[gg * 4 + part] = xv[gg * 4 + part];
    }

    // ---- phase 0: zd A-fragments for both tiles (k<8 real, k=8 -> 1.0 bias row) ----
    v8h aA, aB;
    #pragma unroll
    for (int j = 0; j < 8; ++j) { aA[j] = (_Float16)0.0f; aB[j] = (_Float16)0.0f; }
    if (lane < 16) {
        const float4 f0 = xv[(R0 + lane) * 4 + 0];
        const float4 f1 = xv[(R0 + lane) * 4 + 1];
        aA[0] = (_Float16)f0.x; aA[1] = (_Float16)f0.y; aA[2] = (_Float16)f0.z; aA[3] = (_Float16)f0.w;
        aA[4] = (_Float16)f1.x; aA[5] = (_Float16)f1.y; aA[6] = (_Float16)f1.z; aA[7] = (_Float16)f1.w;
        const float4 g0 = xv[(R0 + 16 + lane) * 4 + 0];
        const float4 g1 = xv[(R0 + 16 + lane) * 4 + 1];
        aB[0] = (_Float16)g0.x; aB[1] = (_Float16)g0.y; aB[2] = (_Float16)g0.z; aB[3] = (_Float16)g0.w;
        aB[4] = (_Float16)g1.x; aB[5] = (_Float16)g1.y; aB[6] = (_Float16)g1.z; aB[7] = (_Float16)g1.w;
    }
    if (q == 1) { aA[0] = (_Float16)1.0f; aB[0] = (_Float16)1.0f; }   // k=8: bias row

    // ---- phase 1: h1 = tanh(zd @ [w0;b0]) -> seg row-major [m][k], stride 72 ----
    #pragma unroll
    for (int t = 0; t < 4; ++t) {
        const v8h b = wsv[W0_OFF + t * 64 + lane];
        v4f cA = __builtin_amdgcn_mfma_f32_16x16x32_f16(aA, b, (v4f)(0.0f), 0, 0, 0);
        v4f cB = __builtin_amdgcn_mfma_f32_16x16x32_f16(aB, b, (v4f)(0.0f), 0, 0, 0);
        const int n = t * 16 + l15;
        #pragma unroll
        for (int rg = 0; rg < 4; ++rg) {
            segA[(q * 4 + rg) * 72 + n] = (_Float16)fast_tanh(cA[rg]);
            segB[(q * 4 + rg) * 72 + n] = (_Float16)fast_tanh(cB[rg]);
        }
    }

    // ---- phase 2: h2 = tanh(h1 @ [w1;b1]) ----
    v8h A0A, A1A, A0B, A1B;
    {
        A0A = *(const v8h*)&segA[l15 * 72 + q * 8];
        A1A = *(const v8h*)&segA[l15 * 72 + 32 + q * 8];
        A0B = *(const v8h*)&segB[l15 * 72 + q * 8];
        A1B = *(const v8h*)&segB[l15 * 72 + 32 + q * 8];
        if (q == 2) { A1A[2] = (_Float16)1.0f; A1B[2] = (_Float16)1.0f; }   // k=50: bias row
        #pragma unroll
        for (int t = 0; t < 4; ++t) {
            const v8h bf0 = wsv[W1_OFF + t * 64 + lane];
            const v8h bf1 = wsv[W1_OFF + 256 + t * 64 + lane];
            v4f cA = __builtin_amdgcn_mfma_f32_16x16x32_f16(A0A, bf0, (v4f)(0.0f), 0, 0, 0);
            cA = __builtin_amdgcn_mfma_f32_16x16x32_f16(A1A, bf1, cA, 0, 0, 0);
            v4f cB = __builtin_amdgcn_mfma_f32_16x16x32_f16(A0B, bf0, (v4f)(0.0f), 0, 0, 0);
            cB = __builtin_amdgcn_mfma_f32_16x16x32_f16(A1B, bf1, cB, 0, 0, 0);
            const int n = t * 16 + l15;
            #pragma unroll
            for (int rg = 0; rg < 4; ++rg) {
                segA[(q * 4 + rg) * 72 + n] = (_Float16)fast_tanh(cA[rg]);
                segB[(q * 4 + rg) * 72 + n] = (_Float16)fast_tanh(cB[rg]);
            }
        }
    }

    // ---- phase 3 A-frags (reload h2) ----
    A0A = *(const v8h*)&segA[l15 * 72 + q * 8];
    A1A = *(const v8h*)&segA[l15 * 72 + 32 + q * 8];
    A0B = *(const v8h*)&segB[l15 * 72 + q * 8];
    A1B = *(const v8h*)&segB[l15 * 72 + 32 + q * 8];
    if (q == 2) { A1A[2] = (_Float16)1.0f; A1B[2] = (_Float16)1.0f; }   // k=50: bias row

    float ldacc = 0.0f;

    // ---- phase 3 first half: dims 0-3 (t = 0..7) ----
    #pragma unroll 2
    for (int t = 0; t < 8; ++t) {
        const v8h bf0 = wsv[WC_OFF + t * 64 + lane];
        const v8h bf1 = wsv[WC_OFF + 1024 + t * 64 + lane];
        v4f cA = __builtin_amdgcn_mfma_f32_16x16x32_f16(A0A, bf0, (v4f)(0.0f), 0, 0, 0);
        cA = __builtin_amdgcn_mfma_f32_16x16x32_f16(A1A, bf1, cA, 0, 0, 0);
        v4f cB = __builtin_amdgcn_mfma_f32_16x16x32_f16(A0B, bf0, (v4f)(0.0f), 0, 0, 0);
        cB = __builtin_amdgcn_mfma_f32_16x16x32_f16(A1B, bf1, cB, 0, 0, 0);
        const int cp = t * 16 + l15;
        #pragma unroll
        for (int rg = 0; rg < 4; ++rg) {
            segA[(q * 4 + rg) * SROW + cp] = (_Float16)cA[rg];
            segB[(q * 4 + rg) * SROW + cp] = (_Float16)cB[rg];
        }
    }

    // ---- epilogue tasks tt=0 (d = q): overlaps with second-half fragment loads below ----
    spline_task(segA, l15 * SROW + q * 32, uA0, R0 + l15, q, out, ldacc);
    spline_task(segB, l15 * SROW + q * 32, uB0, R0 + 16 + l15, q, out, ldacc);

    // ---- phase 3 second half: dims 4-7 (t = 8..15) ----
    #pragma unroll 2
    for (int t = 8; t < 16; ++t) {
        const v8h bf0 = wsv[WC_OFF + t * 64 + lane];
        const v8h bf1 = wsv[WC_OFF + 1024 + t * 64 + lane];
        v4f cA = __builtin_amdgcn_mfma_f32_16x16x32_f16(A0A, bf0, (v4f)(0.0f), 0, 0, 0);
        cA = __builtin_amdgcn_mfma_f32_16x16x32_f16(A1A, bf1, cA, 0, 0, 0);
        v4f cB = __builtin_amdgcn_mfma_f32_16x16x32_f16(A0B, bf0, (v4f)(0.0f), 0, 0, 0);
        cB = __builtin_amdgcn_mfma_f32_16x16x32_f16(A1B, bf1, cB, 0, 0, 0);
        const int cp = t * 16 + l15;
        #pragma unroll
        for (int rg = 0; rg < 4; ++rg) {
            segA[(q * 4 + rg) * SROW + cp] = (_Float16)cA[rg];
            segB[(q * 4 + rg) * SROW + cp] = (_Float16)cB[rg];
        }
    }

    // ---- epilogue tasks tt=1 (d = q+4) ----
    spline_task(segA, l15 * SROW + (q + 4) * 32, uA1, R0 + l15, q + 4, out, ldacc);
    spline_task(segB, l15 * SROW + (q + 4) * 32, uB1, R0 + 16 + l15, q + 4, out, ldacc);

    // ---- logdet: wave shuffle-reduce -> slot-spread atomics (64 slots) ----
    #pragma unroll
    for (int off = 32; off > 0; off >>= 1) ldacc += __shfl_down(ldacc, off);
    if (lane == 0) atomicAdd(&slots[blockIdx.x & 63], ldacc);
}

// ---- finish: sum the 64 partial slots into the scalar logdet output ----
__global__ void nsf_finish(const float* __restrict__ slots, float* __restrict__ ldp) {
    float v = slots[threadIdx.x];
    #pragma unroll
    for (int off = 32; off > 0; off >>= 1) v += __shfl_down(v, off);
    if (threadIdx.x == 0) *ldp = v;
}

extern "C" void kernel_launch(void* const* d_in, const int* in_sizes, int n_in,
                              void* d_out, int out_size, void* d_ws, size_t ws_size,
                              hipStream_t stream) {
    const float* x  = (const float*)d_in[0];
    const float* w0 = (const float*)d_in[1];
    const float* b0 = (const float*)d_in[2];
    const float* w1 = (const float*)d_in[3];
    const float* b1 = (const float*)d_in[4];
    const float* ww = (const float*)d_in[5];
    const float* bw = (const float*)d_in[6];
    const float* wh = (const float*)d_in[7];
    const float* bh = (const float*)d_in[8];
    const float* wd = (const float*)d_in[9];
    const float* bd = (const float*)d_in[10];

    float* out = (float*)d_out;
    float* ldp = out + (size_t)NROWS * 16;   // scalar logdet sum slot
    v8h* wsv = (v8h*)d_ws;                   // 45 KB packed B-fragments (bias folded)
    float* wsf = (float*)d_ws;               // f32 view for slots
    float* slots = wsf + SLOTS_OFF;

    hipLaunchKernelGGL(nsf_prep, dim3((FRAG_TOTAL + 255) / 256), dim3(256), 0, stream,
                       w0, b0, w1, b1, ww, bw, wh, bh, wd, bd, wsv, wsf);
    hipLaunchKernelGGL(nsf_main, dim3(NROWS / 32), dim3(64), 0, stream,
                       x, wsv, out, slots);
    hipLaunchKernelGGL(nsf_finish, dim3(1), dim3(64), 0, stream, slots, ldp);
}